// Round 9
// baseline (2236.087 us; speedup 1.0000x reference)
//
#include <hip/hip_runtime.h>
#include <math.h>
#include <stdint.h>

#define NBATCH 2
#define NPTS 50000
#define NSP  4000
#define NC   24                 // cells per axis
#define NCL  (NC * NC * NC)     // 13824 linear cells
#define CELL 0.35f
#define INVC (1.0f / CELL)
#define ORG  4.2f               // grid covers [-4.2, 4.2); 24 * 0.35 = 8.4
#define CAP  640                // per-wave LDS candidate tile (float4); 4 waves -> 40 KB
#define THRESH 72               // box spoint count needed to trust k_start
#define BIG  3.4e38f

#define MED3(a,b,c) __builtin_amdgcn_fmed3f((a),(b),(c))

__device__ __forceinline__ int cellc(float x) {
    int c = (int)floorf((x + ORG) * INVC);
    return min(max(c, 0), NC - 1);
}
// Wave-local LDS ordering (NO block barrier anywhere in the main kernel).
__device__ __forceinline__ void wave_fence() {
    asm volatile("s_waitcnt lgkmcnt(0)" ::: "memory");
}

// ---------------- preprocessing ----------------

__global__ void bin_kernel(const float* __restrict__ pts, const float* __restrict__ spts,
                           int* __restrict__ sp_cnt, int* __restrict__ pt_cnt) {
    const int t = blockIdx.x * 256 + threadIdx.x;
    if (t < NBATCH * NSP) {
        const int b = t / NSP, j = t - b * NSP;
        const float* s = spts + ((size_t)b * NSP + j) * 3;
        const int cc = (cellc(s[2]) * NC + cellc(s[1])) * NC + cellc(s[0]);
        atomicAdd(&sp_cnt[b * NCL + cc], 1);
    } else if (t < NBATCH * NSP + NBATCH * NPTS) {
        const int u = t - NBATCH * NSP;
        const int b = u / NPTS, i = u - b * NPTS;
        const float* p = pts + ((size_t)b * NPTS + i) * 3;
        const int cc = (cellc(p[2]) * NC + cellc(p[1])) * NC + cellc(p[0]);
        atomicAdd(&pt_cnt[b * NCL + cc], 1);
    }
}

// 6 blocks: 0,1 sp-prefix; 2,3 pt-prefix; 4,5 SAT -> global.
__global__ void prefix_sat_kernel(int* __restrict__ sp_cnt, int* __restrict__ sp_start,
                                  int* __restrict__ sp_cur,
                                  int* __restrict__ pt_cnt, int* __restrict__ pt_start,
                                  int* __restrict__ pt_cur, int* __restrict__ sat) {
    __shared__ union {
        struct { int wsum[16], wpre[16], stot; } p;
        int sat[NCL];
    } sh;
    const int role = blockIdx.x;
    if (role < 4) {
        const bool ispt = role >= 2;
        const int b = role & 1;
        int* cnt = (ispt ? pt_cnt : sp_cnt) + b * NCL;
        int* st  = (ispt ? pt_start : sp_start) + b * (NCL + 1);
        int* cu  = (ispt ? pt_cur : sp_cur) + b * NCL;
        const int lane = threadIdx.x & 63, wid = threadIdx.x >> 6;
        int carry = 0;
        for (int base = 0; base < NCL; base += 1024) {
            const int i = base + (int)threadIdx.x;
            const int v = (i < NCL) ? cnt[i] : 0;
            int s = v;
#pragma unroll
            for (int o = 1; o < 64; o <<= 1) { int t2 = __shfl_up(s, o); if (lane >= o) s += t2; }
            if (lane == 63) sh.p.wsum[wid] = s;
            __syncthreads();
            if (threadIdx.x == 0) {
                int a = 0;
                for (int w = 0; w < 16; ++w) { sh.p.wpre[w] = a; a += sh.p.wsum[w]; }
                sh.p.stot = a;
            }
            __syncthreads();
            const int exc = carry + sh.p.wpre[wid] + s - v;
            if (i < NCL) { st[i] = exc; cu[i] = exc; }
            carry += sh.p.stot;
            __syncthreads();
        }
        if (threadIdx.x == 0) st[NCL] = carry;
    } else {
        const int b = role - 4;
        for (int i = threadIdx.x; i < NCL; i += 1024) sh.sat[i] = sp_cnt[b * NCL + i];
        __syncthreads();
        if (threadIdx.x < NC * NC) {            // x-scan
            const int z = threadIdx.x / NC, y = threadIdx.x % NC;
            const int base = (z * NC + y) * NC;
            int acc = 0;
            for (int x = 0; x < NC; ++x) { acc += sh.sat[base + x]; sh.sat[base + x] = acc; }
        }
        __syncthreads();
        if (threadIdx.x < NC * NC) {            // y-scan
            const int z = threadIdx.x / NC, x = threadIdx.x % NC;
            int acc = 0;
            for (int y = 0; y < NC; ++y) {
                const int idx = (z * NC + y) * NC + x;
                acc += sh.sat[idx]; sh.sat[idx] = acc;
            }
        }
        __syncthreads();
        if (threadIdx.x < NC * NC) {            // z-scan
            const int y = threadIdx.x / NC, x = threadIdx.x % NC;
            int acc = 0;
            for (int z = 0; z < NC; ++z) {
                const int idx = (z * NC + y) * NC + x;
                acc += sh.sat[idx]; sh.sat[idx] = acc;
            }
        }
        __syncthreads();
        for (int i = threadIdx.x; i < NCL; i += 1024) sat[b * NCL + i] = sh.sat[i];
    }
}

__global__ void scatter_kernel(const float* __restrict__ pts, const float* __restrict__ spts,
                               int* __restrict__ sp_cur, int* __restrict__ pt_cur,
                               float4* __restrict__ ssp, int* __restrict__ perm) {
    const int t = blockIdx.x * 256 + threadIdx.x;
    if (t < NBATCH * NSP) {
        const int b = t / NSP, j = t - b * NSP;
        const float* s = spts + ((size_t)b * NSP + j) * 3;
        const float x = s[0], y = s[1], z = s[2];
        const int cc = (cellc(z) * NC + cellc(y)) * NC + cellc(x);
        const int pos = atomicAdd(&sp_cur[b * NCL + cc], 1);
        ssp[b * NSP + pos] = make_float4(x, y, z, 0.f);
    } else if (t < NBATCH * NSP + NBATCH * NPTS) {
        const int u = t - NBATCH * NSP;
        const int b = u / NPTS, i = u - b * NPTS;
        const float* p = pts + ((size_t)b * NPTS + i) * 3;
        const int cc = (cellc(p[2]) * NC + cellc(p[1])) * NC + cellc(p[0]);
        const int pos = atomicAdd(&pt_cur[b * NCL + cc], 1);
        perm[b * NPTS + pos] = i;
    }
}

// ---------------- main kernel ----------------

__device__ __forceinline__ int satg(const int* __restrict__ s, int x, int y, int z) {
    if (x < 0 || y < 0 || z < 0) return 0;
    x = min(x, NC - 1); y = min(y, NC - 1); z = min(z, NC - 1);
    return s[(z * NC + y) * NC + x];
}
__device__ __forceinline__ int boxcount(const int* __restrict__ s, int x0, int x1,
                                        int y0, int y1, int z0, int z1) {
    return satg(s, x1, y1, z1) - satg(s, x0 - 1, y1, z1) - satg(s, x1, y0 - 1, z1)
         - satg(s, x1, y1, z0 - 1) + satg(s, x0 - 1, y0 - 1, z1)
         + satg(s, x0 - 1, y1, z0 - 1) + satg(s, x1, y0 - 1, z0 - 1)
         - satg(s, x0 - 1, y0 - 1, z0 - 1);
}

// Wave-private gather of box_k (shell=false) or box_k \ box_{k-1} (shell=true)
// into this wave's LDS tile, appending; scans exactly-once via `scanned`.
// NO block barriers: wave prefix via shfl, LDS ordering via wave_fence().
template <class F>
__device__ __forceinline__ void wave_gather_scan(
    int k, bool shell,
    int mnx, int mxx, int mny, int mxy, int mnz, int mxz,
    const int* __restrict__ st, const float4* __restrict__ sspb,
    float4* __restrict__ tile, int lane,
    int& fill, int& scanned, bool& flushed, F&& body)
{
    const int xlo = mnx - k, ylo = mny - k, zlo = mnz - k;
    const int nx = mxx - mnx + 1 + 2 * k;
    const int ny = mxy - mny + 1 + 2 * k;
    const int nz = mxz - mnz + 1 + 2 * k;
    const int nxy = nx * ny;
    const int ncells = nxy * nz;
    for (int base = 0; base < ncells; base += 64) {
        const int idx = base + lane;
        int cnt = 0, src = 0;
        if (idx < ncells) {
            const int cz = idx / nxy;
            const int r  = idx - cz * nxy;
            const int cy = r / nx;
            const int cx = r - cy * nx;
            const bool skip = shell && cx >= 1 && cx <= nx - 2 &&
                              cy >= 1 && cy <= ny - 2 && cz >= 1 && cz <= nz - 2;
            const int ax = xlo + cx, ay = ylo + cy, az = zlo + cz;
            if (!skip && (unsigned)ax < NC && (unsigned)ay < NC && (unsigned)az < NC) {
                const int c = (az * NC + ay) * NC + ax;
                src = st[c];
                cnt = st[c + 1] - src;
            }
        }
        int s = cnt;
#pragma unroll
        for (int o = 1; o < 64; o <<= 1) { const int t2 = __shfl_up(s, o); if (lane >= o) s += t2; }
        const int total = __shfl(s, 63);          // wave-uniform
        int dst  = fill + (s - cnt);
        int rem  = cnt;
        int srcp = src;
        int newfill = fill + total;               // wave-uniform
        while (newfill > CAP) {                   // rare overflow: flush-scan
            flushed = true;
            while (rem > 0 && dst < CAP) {
                const float4 v = sspb[srcp];
                tile[dst] = make_float4(v.x, v.y, v.z, __int_as_float(srcp));
                ++dst; ++srcp; --rem;
            }
            wave_fence();
            for (int i = scanned; i < CAP; ++i) {
                const float4 sv = tile[i];
                body(sv.x, sv.y, sv.z, __float_as_int(sv.w));
            }
            wave_fence();
            dst -= CAP; newfill -= CAP; scanned = 0;
        }
        while (rem > 0) {
            const float4 v = sspb[srcp];
            tile[dst] = make_float4(v.x, v.y, v.z, __int_as_float(srcp));
            ++dst; ++srcp; --rem;
        }
        fill = newfill;
    }
    wave_fence();
    for (int i = scanned; i < fill; ++i) {
        const float4 sv = tile[i];
        body(sv.x, sv.y, sv.z, __float_as_int(sv.w));
    }
    scanned = fill;
}

__global__ __launch_bounds__(256, 4) void voronoi_main(
    const float* __restrict__ pts,
    const int* __restrict__ sp_start,
    const float4* __restrict__ ssp,
    const int* __restrict__ perm,
    const int* __restrict__ sat,
    float* __restrict__ out)
{
    __shared__ float4 sh_tile[4][CAP];           // per-wave private tiles, 40 KB

    const int lane = threadIdx.x & 63;
    const int wv   = __builtin_amdgcn_readfirstlane(threadIdx.x >> 6);
    const int b    = blockIdx.y;
    const int g    = blockIdx.x * 4 + wv;        // independent 64-point group per wave
    if (g * 64 >= NPTS) return;                  // wave-uniform exit

    float4* tile = &sh_tile[wv][0];

    int sidx = g * 64 + lane;
    const bool valid = (sidx < NPTS);
    sidx = min(sidx, NPTS - 1);
    const int orig = perm[b * NPTS + sidx];
    const float* pp = pts + ((size_t)b * NPTS + orig) * 3;
    const float px = pp[0], py = pp[1], pz = pp[2];
    const int icx = cellc(px), icy = cellc(py), icz = cellc(pz);

    // Wave bbox via butterfly (all lanes end with the wave min/max).
    int mnx = icx, mxx = icx, mny = icy, mxy = icy, mnz = icz, mxz = icz;
#pragma unroll
    for (int o = 1; o < 64; o <<= 1) {
        mnx = min(mnx, __shfl_xor(mnx, o)); mxx = max(mxx, __shfl_xor(mxx, o));
        mny = min(mny, __shfl_xor(mny, o)); mxy = max(mxy, __shfl_xor(mxy, o));
        mnz = min(mnz, __shfl_xor(mnz, o)); mxz = max(mxz, __shfl_xor(mxz, o));
    }
    mnx = __builtin_amdgcn_readfirstlane(mnx); mxx = __builtin_amdgcn_readfirstlane(mxx);
    mny = __builtin_amdgcn_readfirstlane(mny); mxy = __builtin_amdgcn_readfirstlane(mxy);
    mnz = __builtin_amdgcn_readfirstlane(mnz); mxz = __builtin_amdgcn_readfirstlane(mxz);

    // k_start: lanes 0..23 probe k=1..24 against the SAT in parallel.
    const int* satb = sat + b * NCL;
    bool ok = false;
    if (lane < 24) {
        const int kq = lane + 1;
        const int c = boxcount(satb, mnx - kq, mxx + kq, mny - kq, mxy + kq,
                               mnz - kq, mxz + kq);
        ok = (c >= THRESH);
    }
    const unsigned long long mb = __ballot(ok);   // bit23 always set (whole grid=4000)
    int k = __builtin_amdgcn_readfirstlane((int)__ffsll((long long)mb));  // = k_start

    const int* st = sp_start + b * (NCL + 1);
    const float4* sspb = ssp + (size_t)b * NSP;

    // Per-lane FULL top-11 (no cross-wave merge needed).
    float d0 = BIG, d1 = BIG, d2 = BIG, d3 = BIG, d4 = BIG, d5 = BIG;
    float d6 = BIG, d7 = BIG, d8 = BIG, d9 = BIG, d10 = BIG;
    int i0 = 0;

    auto bodyA = [&](float sx, float sy, float sz, int t) {
        const float dx = px - sx, dy = py - sy, dz = pz - sz;
        const float nd = fmaf(dx, dx, fmaf(dy, dy, dz * dz));
        d10 = MED3(d9, d10, nd); d9 = MED3(d8, d9, nd); d8 = MED3(d7, d8, nd);
        d7  = MED3(d6, d7,  nd); d6 = MED3(d5, d6, nd); d5 = MED3(d4, d5, nd);
        d4  = MED3(d3, d4,  nd); d3 = MED3(d2, d3, nd); d2 = MED3(d1, d2, nd);
        d1  = MED3(d0, d1,  nd);
        i0 = (nd < d0) ? t : i0;
        d0 = fminf(d0, nd);
    };

    int fill = 0, scanned = 0;
    bool flushed = false;
    wave_gather_scan(k, false, mnx, mxx, mny, mxy, mnz, mxz,
                     st, sspb, tile, lane, fill, scanned, flushed, bodyA);

    for (;;) {
        const bool covered = (mnx - k <= 0) && (mny - k <= 0) && (mnz - k <= 0) &&
                             (mxx + k >= NC - 1) && (mxy + k >= NC - 1) && (mxz + k >= NC - 1);
        const float bnd = (float)k * CELL;
        if (covered || !__any(d10 > bnd * bnd)) break;
        ++k;                                      // rare exact expansion
        wave_gather_scan(k, true, mnx, mxx, mny, mxy, mnz, mxz,
                         st, sspb, tile, lane, fill, scanned, flushed, bodyA);
    }

    // Per-lane nearest + edge scan (pass B).
    const int i0g = i0;
    const float4 cpt = sspb[i0g];
    const float ix = cpt.x, iy = cpt.y, iz = cpt.z;
    const float vx = px - ix, vy = py - iy, vz = pz - iz;
    const float d10f = d10;
    float best = BIG;

    auto bodyB = [&](float sx, float sy, float sz, int t) {
        const float dx = px - sx, dy = py - sy, dz = pz - sz;
        const float nd = fmaf(dx, dx, fmaf(dy, dy, dz * dz));
        const bool adm = (nd <= d10f) && (t != i0g);
        const float ex = sx - ix, ey = sy - iy, ez = sz - iz;
        const float ee = fmaxf(fmaf(ex, ex, fmaf(ey, ey, ez * ez)), 1e-30f);
        const float dt = fmaf(vx, ex, fmaf(vy, ey, vz * ez));
        const float u  = fmaf(-0.5f, ee, dt);
        const float t2 = u * u * __builtin_amdgcn_rcpf(ee);
        best = adm ? fminf(best, t2) : best;
    };

    if (!flushed) {
        // Tile still holds the entire final box (gather appended across shells).
        for (int i = 0; i < fill; ++i) {
            const float4 sv = tile[i];
            bodyB(sv.x, sv.y, sv.z, __float_as_int(sv.w));
        }
    } else {
        int f2 = 0, s2 = 0; bool fl2 = false;
        wave_gather_scan(k, false, mnx, mxx, mny, mxy, mnz, mxz,
                         st, sspb, tile, lane, f2, s2, fl2, bodyB);
    }

    if (valid) out[(size_t)b * NPTS + orig] = best;
}

// ---------------- launch ----------------

extern "C" void kernel_launch(void* const* d_in, const int* in_sizes, int n_in,
                              void* d_out, int out_size, void* d_ws, size_t ws_size,
                              hipStream_t stream) {
    const float* pts  = (const float*)d_in[0];   // (2, 50000, 3)
    const float* spts = (const float*)d_in[1];   // (2, 4000, 3)
    float* out = (float*)d_out;                  // (2, 50000)

    int* W = (int*)d_ws;
    int* sp_cnt   = W;                            // 2*NCL
    int* pt_cnt   = sp_cnt + 2 * NCL;             // 2*NCL
    int* sp_start = pt_cnt + 2 * NCL;             // 2*(NCL+1)
    int* pt_start = sp_start + 2 * (NCL + 1);     // 2*(NCL+1)
    int* sp_cur   = pt_start + 2 * (NCL + 1);     // 2*NCL
    int* pt_cur   = sp_cur + 2 * NCL;             // 2*NCL
    int* sat      = pt_cur + 2 * NCL;             // 2*NCL
    int* perm     = sat + 2 * NCL;                // 2*NPTS
    float4* ssp   = (float4*)(((uintptr_t)(perm + 2 * NPTS) + 15) & ~(uintptr_t)15);

    hipMemsetAsync(W, 0, (size_t)(4 * NCL) * sizeof(int), stream);

    const int npre = (NBATCH * NSP + NBATCH * NPTS + 255) / 256;
    bin_kernel<<<npre, 256, 0, stream>>>(pts, spts, sp_cnt, pt_cnt);
    prefix_sat_kernel<<<6, 1024, 0, stream>>>(sp_cnt, sp_start, sp_cur,
                                              pt_cnt, pt_start, pt_cur, sat);
    scatter_kernel<<<npre, 256, 0, stream>>>(pts, spts, sp_cur, pt_cur, ssp, perm);

    const int ngrp = (NPTS + 63) / 64;            // 782 independent wave-groups
    dim3 grid((ngrp + 3) / 4, NBATCH);
    voronoi_main<<<grid, 256, 0, stream>>>(pts, sp_start, ssp, perm, sat, out);
}

// Round 10
// 800.486 us; speedup vs baseline: 2.7934x; 2.7934x over previous
//
#include <hip/hip_runtime.h>
#include <math.h>
#include <stdint.h>

#define NBATCH 2
#define NPTS 50000
#define NSP  4000
#define NC   24                 // cells per axis (spoint CSR grid)
#define NCL  (NC * NC * NC)     // 13824 linear cells
#define NCM  32768              // morton code space for point sorting (32^3)
#define CELL 0.35f
#define INVC (1.0f / CELL)
#define ORG  4.2f               // grid covers [-4.2, 4.2); 24 * 0.35 = 8.4
#define CAP  640                // per-wave LDS candidate tile (float4); 4 waves -> 40 KB
#define THRESH 72               // box spoint count needed to trust k_start
#define BIG  3.4e38f

#define MED3(a,b,c) __builtin_amdgcn_fmed3f((a),(b),(c))

__device__ __forceinline__ int cellc(float x) {
    int c = (int)floorf((x + ORG) * INVC);
    return min(max(c, 0), NC - 1);
}
__device__ __forceinline__ unsigned spread3(unsigned x) {
    x &= 0x3ff;
    x = (x | (x << 16)) & 0x030000FFu;
    x = (x | (x << 8))  & 0x0300F00Fu;
    x = (x | (x << 4))  & 0x030C30C3u;
    x = (x | (x << 2))  & 0x09249249u;
    return x;
}
// Wave-local LDS ordering (NO block barrier anywhere in the main kernel).
__device__ __forceinline__ void wave_fence() {
    asm volatile("s_waitcnt lgkmcnt(0)" ::: "memory");
}

// ---------------- preprocessing ----------------

__global__ void bin_kernel(const float* __restrict__ pts, const float* __restrict__ spts,
                           int* __restrict__ sp_cnt, int* __restrict__ pt_cnt) {
    const int t = blockIdx.x * 256 + threadIdx.x;
    if (t < NBATCH * NSP) {
        const int b = t / NSP, j = t - b * NSP;
        const float* s = spts + ((size_t)b * NSP + j) * 3;
        const int cc = (cellc(s[2]) * NC + cellc(s[1])) * NC + cellc(s[0]);
        atomicAdd(&sp_cnt[b * NCL + cc], 1);
    } else if (t < NBATCH * NSP + NBATCH * NPTS) {
        const int u = t - NBATCH * NSP;
        const int b = u / NPTS, i = u - b * NPTS;
        const float* p = pts + ((size_t)b * NPTS + i) * 3;
        const unsigned m = spread3(cellc(p[0])) | (spread3(cellc(p[1])) << 1)
                         | (spread3(cellc(p[2])) << 2);
        atomicAdd(&pt_cnt[b * NCM + m], 1);
    }
}

// 6 blocks: 0,1 sp-prefix (NCL); 2,3 pt-prefix (NCM); 4,5 SAT -> global.
__global__ void prefix_sat_kernel(int* __restrict__ sp_cnt, int* __restrict__ sp_start,
                                  int* __restrict__ sp_cur,
                                  int* __restrict__ pt_cnt, int* __restrict__ pt_start,
                                  int* __restrict__ pt_cur, int* __restrict__ sat) {
    __shared__ union {
        struct { int wsum[16], wpre[16], stot; } p;
        int sat[NCL];
    } sh;
    const int role = blockIdx.x;
    if (role < 4) {
        const bool ispt = role >= 2;
        const int b = role & 1;
        const int n = ispt ? NCM : NCL;
        int* cnt = (ispt ? pt_cnt : sp_cnt) + b * n;
        int* st  = (ispt ? pt_start : sp_start) + b * (n + 1);
        int* cu  = (ispt ? pt_cur : sp_cur) + b * n;
        const int lane = threadIdx.x & 63, wid = threadIdx.x >> 6;
        int carry = 0;
        for (int base = 0; base < n; base += 1024) {
            const int i = base + (int)threadIdx.x;
            const int v = (i < n) ? cnt[i] : 0;
            int s = v;
#pragma unroll
            for (int o = 1; o < 64; o <<= 1) { int t2 = __shfl_up(s, o); if (lane >= o) s += t2; }
            if (lane == 63) sh.p.wsum[wid] = s;
            __syncthreads();
            if (threadIdx.x == 0) {
                int a = 0;
                for (int w = 0; w < 16; ++w) { sh.p.wpre[w] = a; a += sh.p.wsum[w]; }
                sh.p.stot = a;
            }
            __syncthreads();
            const int exc = carry + sh.p.wpre[wid] + s - v;
            if (i < n) { st[i] = exc; cu[i] = exc; }
            carry += sh.p.stot;
            __syncthreads();
        }
        if (threadIdx.x == 0) st[n] = carry;
    } else {
        const int b = role - 4;
        for (int i = threadIdx.x; i < NCL; i += 1024) sh.sat[i] = sp_cnt[b * NCL + i];
        __syncthreads();
        if (threadIdx.x < NC * NC) {            // x-scan
            const int z = threadIdx.x / NC, y = threadIdx.x % NC;
            const int base = (z * NC + y) * NC;
            int acc = 0;
            for (int x = 0; x < NC; ++x) { acc += sh.sat[base + x]; sh.sat[base + x] = acc; }
        }
        __syncthreads();
        if (threadIdx.x < NC * NC) {            // y-scan
            const int z = threadIdx.x / NC, x = threadIdx.x % NC;
            int acc = 0;
            for (int y = 0; y < NC; ++y) {
                const int idx = (z * NC + y) * NC + x;
                acc += sh.sat[idx]; sh.sat[idx] = acc;
            }
        }
        __syncthreads();
        if (threadIdx.x < NC * NC) {            // z-scan
            const int y = threadIdx.x / NC, x = threadIdx.x % NC;
            int acc = 0;
            for (int z = 0; z < NC; ++z) {
                const int idx = (z * NC + y) * NC + x;
                acc += sh.sat[idx]; sh.sat[idx] = acc;
            }
        }
        __syncthreads();
        for (int i = threadIdx.x; i < NCL; i += 1024) sat[b * NCL + i] = sh.sat[i];
    }
}

__global__ void scatter_kernel(const float* __restrict__ pts, const float* __restrict__ spts,
                               int* __restrict__ sp_cur, int* __restrict__ pt_cur,
                               float4* __restrict__ ssp, int* __restrict__ perm) {
    const int t = blockIdx.x * 256 + threadIdx.x;
    if (t < NBATCH * NSP) {
        const int b = t / NSP, j = t - b * NSP;
        const float* s = spts + ((size_t)b * NSP + j) * 3;
        const float x = s[0], y = s[1], z = s[2];
        const int cc = (cellc(z) * NC + cellc(y)) * NC + cellc(x);
        const int pos = atomicAdd(&sp_cur[b * NCL + cc], 1);
        ssp[b * NSP + pos] = make_float4(x, y, z, 0.f);
    } else if (t < NBATCH * NSP + NBATCH * NPTS) {
        const int u = t - NBATCH * NSP;
        const int b = u / NPTS, i = u - b * NPTS;
        const float* p = pts + ((size_t)b * NPTS + i) * 3;
        const unsigned m = spread3(cellc(p[0])) | (spread3(cellc(p[1])) << 1)
                         | (spread3(cellc(p[2])) << 2);
        const int pos = atomicAdd(&pt_cur[b * NCM + m], 1);
        perm[b * NPTS + pos] = i;
    }
}

// ---------------- main kernel ----------------

__device__ __forceinline__ int satg(const int* __restrict__ s, int x, int y, int z) {
    if (x < 0 || y < 0 || z < 0) return 0;
    x = min(x, NC - 1); y = min(y, NC - 1); z = min(z, NC - 1);
    return s[(z * NC + y) * NC + x];
}
__device__ __forceinline__ int boxcount(const int* __restrict__ s, int x0, int x1,
                                        int y0, int y1, int z0, int z1) {
    return satg(s, x1, y1, z1) - satg(s, x0 - 1, y1, z1) - satg(s, x1, y0 - 1, z1)
         - satg(s, x1, y1, z0 - 1) + satg(s, x0 - 1, y0 - 1, z1)
         + satg(s, x0 - 1, y1, z0 - 1) + satg(s, x1, y0 - 1, z0 - 1)
         - satg(s, x0 - 1, y0 - 1, z0 - 1);
}

// Wave-private gather+scan of box_k (shell=false) / box_k \ box_{k-1} (shell=true).
// Rows of the box are CONTIGUOUS CSR runs: <=64 run-descriptors per batch, wave
// shfl-prefix, then search-then-load copy -> all global loads independent.
template <class F>
__device__ __forceinline__ void wave_box_scan(
    int k, bool shell,
    int mnx, int mxx, int mny, int mxy, int mnz, int mxz,
    const int* __restrict__ st, const float4* __restrict__ sspb,
    float4* __restrict__ tile, int* __restrict__ pref, int* __restrict__ smini,
    int lane, int& fill, int& scanned, bool& flushed, F&& body)
{
    const int xlo0 = mnx - k, xhi0 = mxx + k;
    const int ylo0 = mny - k, yhi0 = mxy + k;
    const int zlo0 = mnz - k, zhi0 = mxz + k;
    const int xlo = max(xlo0, 0), xhi = min(xhi0, NC - 1);
    const int ylo = max(ylo0, 0), yhi = min(yhi0, NC - 1);
    const int zlo = max(zlo0, 0), zhi = min(zhi0, NC - 1);
    const int ny = yhi - ylo + 1;
    const int nz = zhi - zlo + 1;
    const int nruns = 2 * ny * nz;      // 2 run slots per (y,z) row

    for (int base = 0; base < nruns; base += 64) {
        const int rid = base + lane;
        int cnt = 0, src = 0;
        if (rid < nruns) {
            const int row = rid >> 1, side = rid & 1;
            const int rz = row / ny;
            const int ry = row - rz * ny;
            const int az = zlo + rz, ay = ylo + ry;
            const bool face = !shell || (az == zlo0) || (az == zhi0) ||
                              (ay == ylo0) || (ay == yhi0);
            int xa = 0, xb = -1;
            if (face) {
                if (side == 0) { xa = xlo; xb = xhi; }
            } else {
                if (side == 0) { if (xlo0 >= 0)     { xa = xb = xlo0; } }
                else           { if (xhi0 <= NC-1)  { xa = xb = xhi0; } }
            }
            if (xb >= xa) {
                const int rowb = (az * NC + ay) * NC;
                src = st[rowb + xa];
                cnt = st[rowb + xb + 1] - src;
            }
        }
        // Wave exclusive prefix of run lengths.
        int s = cnt;
#pragma unroll
        for (int o = 1; o < 64; o <<= 1) { const int t2 = __shfl_up(s, o); if (lane >= o) s += t2; }
        const int total = __shfl(s, 63);            // wave-uniform
        if (total == 0) continue;
        pref[lane]  = s - cnt;
        smini[lane] = src - (s - cnt);
        wave_fence();

        int t0 = 0;
        while (t0 < total) {                        // wave-uniform loop
            int room = CAP - fill;
            if (room == 0) {                        // flush: scan resident, reset
                flushed = true;
                for (int i = scanned; i < fill; ++i) {
                    const float4 sv = tile[i];
                    body(sv.x, sv.y, sv.z, __float_as_int(sv.w));
                }
                wave_fence();
                fill = 0; scanned = 0; room = CAP;
            }
            const int take = min(room, total - t0);
            for (int t = t0 + lane; t < t0 + take; t += 64) {
                int lo = 0;                          // largest r with pref[r] <= t
#pragma unroll
                for (int stp = 32; stp > 0; stp >>= 1) {
                    const int m = lo + stp;
                    if (m < 64 && pref[m] <= t) lo = m;
                }
                const int ad = smini[lo] + t;        // sorted-spoint index
                const float4 v = sspb[ad];           // independent loads
                tile[fill + (t - t0)] = make_float4(v.x, v.y, v.z, __int_as_float(ad));
            }
            fill += take; t0 += take;
        }
        wave_fence();                                // pref/smini reused next batch
    }
    wave_fence();
    for (int i = scanned; i < fill; ++i) {
        const float4 sv = tile[i];
        body(sv.x, sv.y, sv.z, __float_as_int(sv.w));
    }
    scanned = fill;
}

__global__ __launch_bounds__(256, 3) void voronoi_main(
    const float* __restrict__ pts,
    const int* __restrict__ sp_start,
    const float4* __restrict__ ssp,
    const int* __restrict__ perm,
    const int* __restrict__ sat,
    float* __restrict__ out)
{
    __shared__ float4 sh_tile[4][CAP];               // per-wave private tiles, 40 KB
    __shared__ int sh_pref[4][64];
    __shared__ int sh_smini[4][64];

    const int lane = threadIdx.x & 63;
    const int wv   = __builtin_amdgcn_readfirstlane(threadIdx.x >> 6);
    const int b    = blockIdx.y;
    const int g    = blockIdx.x * 4 + wv;            // independent 64-pt group per wave
    if (g * 64 >= NPTS) return;                      // wave-uniform exit

    float4* tile = &sh_tile[wv][0];
    int* pref  = &sh_pref[wv][0];
    int* smini = &sh_smini[wv][0];

    int sidx = g * 64 + lane;
    const bool valid = (sidx < NPTS);
    sidx = min(sidx, NPTS - 1);
    const int orig = perm[b * NPTS + sidx];
    const float* pp = pts + ((size_t)b * NPTS + orig) * 3;
    const float px = pp[0], py = pp[1], pz = pp[2];
    const int icx = cellc(px), icy = cellc(py), icz = cellc(pz);

    // Wave bbox via butterfly.
    int mnx = icx, mxx = icx, mny = icy, mxy = icy, mnz = icz, mxz = icz;
#pragma unroll
    for (int o = 1; o < 64; o <<= 1) {
        mnx = min(mnx, __shfl_xor(mnx, o)); mxx = max(mxx, __shfl_xor(mxx, o));
        mny = min(mny, __shfl_xor(mny, o)); mxy = max(mxy, __shfl_xor(mxy, o));
        mnz = min(mnz, __shfl_xor(mnz, o)); mxz = max(mxz, __shfl_xor(mxz, o));
    }
    mnx = __builtin_amdgcn_readfirstlane(mnx); mxx = __builtin_amdgcn_readfirstlane(mxx);
    mny = __builtin_amdgcn_readfirstlane(mny); mxy = __builtin_amdgcn_readfirstlane(mxy);
    mnz = __builtin_amdgcn_readfirstlane(mnz); mxz = __builtin_amdgcn_readfirstlane(mxz);

    // k_start: lanes 0..23 probe k=1..24 against the SAT in parallel.
    const int* satb = sat + b * NCL;
    bool ok = false;
    if (lane < 24) {
        const int kq = lane + 1;
        ok = boxcount(satb, mnx - kq, mxx + kq, mny - kq, mxy + kq,
                      mnz - kq, mxz + kq) >= THRESH;
    }
    const unsigned long long mb = __ballot(ok);      // bit23 always set (grid=4000)
    int k = __builtin_amdgcn_readfirstlane((int)__ffsll((long long)mb));

    const int* st = sp_start + b * (NCL + 1);
    const float4* sspb = ssp + (size_t)b * NSP;

    // Per-lane FULL top-11 (no cross-lane merge needed).
    float d0 = BIG, d1 = BIG, d2 = BIG, d3 = BIG, d4 = BIG, d5 = BIG;
    float d6 = BIG, d7 = BIG, d8 = BIG, d9 = BIG, d10 = BIG;
    int i0 = 0;

    auto bodyA = [&](float sx, float sy, float sz, int t) {
        const float dx = px - sx, dy = py - sy, dz = pz - sz;
        const float nd = fmaf(dx, dx, fmaf(dy, dy, dz * dz));
        d10 = MED3(d9, d10, nd); d9 = MED3(d8, d9, nd); d8 = MED3(d7, d8, nd);
        d7  = MED3(d6, d7,  nd); d6 = MED3(d5, d6, nd); d5 = MED3(d4, d5, nd);
        d4  = MED3(d3, d4,  nd); d3 = MED3(d2, d3, nd); d2 = MED3(d1, d2, nd);
        d1  = MED3(d0, d1,  nd);
        i0 = (nd < d0) ? t : i0;
        d0 = fminf(d0, nd);
    };

    int fill = 0, scanned = 0;
    bool flushed = false;
    wave_box_scan(k, false, mnx, mxx, mny, mxy, mnz, mxz,
                  st, sspb, tile, pref, smini, lane, fill, scanned, flushed, bodyA);

    for (;;) {
        const bool covered = (mnx - k <= 0) && (mny - k <= 0) && (mnz - k <= 0) &&
                             (mxx + k >= NC - 1) && (mxy + k >= NC - 1) && (mxz + k >= NC - 1);
        const float bnd = (float)k * CELL;
        if (covered || !__any(d10 > bnd * bnd)) break;
        ++k;                                         // rare exact expansion
        wave_box_scan(k, true, mnx, mxx, mny, mxy, mnz, mxz,
                      st, sspb, tile, pref, smini, lane, fill, scanned, flushed, bodyA);
    }

    // Pass B: edge scan with per-lane nearest.
    const int i0g = i0;
    const float4 cpt = sspb[i0g];
    const float ix = cpt.x, iy = cpt.y, iz = cpt.z;
    const float vx = px - ix, vy = py - iy, vz = pz - iz;
    const float d10f = d10;
    float best = BIG;

    auto bodyB = [&](float sx, float sy, float sz, int t) {
        const float dx = px - sx, dy = py - sy, dz = pz - sz;
        const float nd = fmaf(dx, dx, fmaf(dy, dy, dz * dz));
        const bool adm = (nd <= d10f) && (t != i0g);
        const float ex = sx - ix, ey = sy - iy, ez = sz - iz;
        const float ee = fmaxf(fmaf(ex, ex, fmaf(ey, ey, ez * ez)), 1e-30f);
        const float dt = fmaf(vx, ex, fmaf(vy, ey, vz * ez));
        const float u  = fmaf(-0.5f, ee, dt);
        const float t2 = u * u * __builtin_amdgcn_rcpf(ee);
        best = adm ? fminf(best, t2) : best;
    };

    if (!flushed) {
        for (int i = 0; i < fill; ++i) {             // tile holds the full final box
            const float4 sv = tile[i];
            bodyB(sv.x, sv.y, sv.z, __float_as_int(sv.w));
        }
    } else {
        int f2 = 0, s2 = 0; bool fl2 = false;
        wave_box_scan(k, false, mnx, mxx, mny, mxy, mnz, mxz,
                      st, sspb, tile, pref, smini, lane, f2, s2, fl2, bodyB);
    }

    if (valid) out[(size_t)b * NPTS + orig] = best;
}

// ---------------- launch ----------------

extern "C" void kernel_launch(void* const* d_in, const int* in_sizes, int n_in,
                              void* d_out, int out_size, void* d_ws, size_t ws_size,
                              hipStream_t stream) {
    const float* pts  = (const float*)d_in[0];   // (2, 50000, 3)
    const float* spts = (const float*)d_in[1];   // (2, 4000, 3)
    float* out = (float*)d_out;                  // (2, 50000)

    int* W = (int*)d_ws;
    int* sp_cnt   = W;                            // 2*NCL
    int* pt_cnt   = sp_cnt + 2 * NCL;             // 2*NCM   (adjacent: one memset)
    int* sp_start = pt_cnt + 2 * NCM;             // 2*(NCL+1)
    int* pt_start = sp_start + 2 * (NCL + 1);     // 2*(NCM+1)
    int* sp_cur   = pt_start + 2 * (NCM + 1);     // 2*NCL
    int* pt_cur   = sp_cur + 2 * NCL;             // 2*NCM
    int* sat      = pt_cur + 2 * NCM;             // 2*NCL
    int* perm     = sat + 2 * NCL;                // 2*NPTS
    float4* ssp   = (float4*)(((uintptr_t)(perm + 2 * NPTS) + 15) & ~(uintptr_t)15);

    hipMemsetAsync(W, 0, (size_t)(2 * NCL + 2 * NCM) * sizeof(int), stream);

    const int npre = (NBATCH * NSP + NBATCH * NPTS + 255) / 256;
    bin_kernel<<<npre, 256, 0, stream>>>(pts, spts, sp_cnt, pt_cnt);
    prefix_sat_kernel<<<6, 1024, 0, stream>>>(sp_cnt, sp_start, sp_cur,
                                              pt_cnt, pt_start, pt_cur, sat);
    scatter_kernel<<<npre, 256, 0, stream>>>(pts, spts, sp_cur, pt_cur, ssp, perm);

    const int ngrp = (NPTS + 63) / 64;            // 782 independent wave-groups
    dim3 grid((ngrp + 3) / 4, NBATCH);
    voronoi_main<<<grid, 256, 0, stream>>>(pts, sp_start, ssp, perm, sat, out);
}